// Round 23
// baseline (135.434 us; speedup 1.0000x reference)
//
#include <hip/hip_runtime.h>
#include <hip/hip_fp16.h>

// GCN conv: out = scatter-reduce(norm * (xW)[row] -> col) + dinv^2*(xW) + b
// N=100000, E=1600000, IN_C=256, OUT_C=64
// Reordered pipeline for cross-phase overlap:
//   k_scat (2-pass hist + direct block-major pack write, 6 KB LDS)
//   -> k_gb2 {512-thr: MFMA gemm 256-row tiles ||interleaved|| b2 bucket
//      assemble+sort+dinv+premult -> pack2}
//   -> k_reduce (segmented reduce, fp16 gather, 8-edge ILP)

#define BS 256
#define EPB2 4096           // edges per scatter block
#define BSH 8               // bucket = col >> 8
#define CAP 4608            // bucket staging capacity
#define NBK 512             // metadata row stride

typedef unsigned long long u64;
typedef unsigned int u32;
typedef unsigned short u16;
typedef unsigned char u8;

typedef __attribute__((ext_vector_type(8))) short bf16x8;
typedef __attribute__((ext_vector_type(4))) float f32x4;

__device__ inline u16 f2bf(float f) {          // RNE fp32 -> bf16
    u32 u = __float_as_uint(f);
    return (u16)((u + 0x7fffu + ((u >> 16) & 1u)) >> 16);
}
__device__ inline u32 pack2bf(float a, float b) {
    return (u32)f2bf(a) | ((u32)f2bf(b) << 16);
}

// ---- scatter: 2-pass hist + direct cursor write into block-major pack ----
__global__ __launch_bounds__(BS) void k_scat(const int* __restrict__ row,
                                             const int* __restrict__ col,
                                             const float* __restrict__ ew,
                                             u16* __restrict__ cntg,
                                             u16* __restrict__ scng,
                                             u64* __restrict__ pack, int e) {
    __shared__ u32 cnt[512];
    __shared__ u32 scn[512];
    __shared__ u32 lpos[512];
    const int tid = threadIdx.x;
    int blk = blockIdx.x;
    int base = blk * EPB2;
    int ej = e - base; if (ej > EPB2) ej = EPB2;

    cnt[tid] = 0; cnt[tid + 256] = 0;
    __syncthreads();
#pragma unroll
    for (int j = 0; j < 16; ++j) {
        int lj = j * BS + tid;
        if (lj < ej) atomicAdd(&cnt[col[base + lj] >> BSH], 1u);
    }
    __syncthreads();
    scn[tid] = cnt[tid];
    scn[tid + 256] = cnt[tid + 256];
    __syncthreads();
    for (int off = 1; off < 512; off <<= 1) {
        u32 a0 = (tid >= off) ? scn[tid - off] : 0u;
        u32 a1 = scn[tid + 256 - off];
        __syncthreads();
        scn[tid] += a0;
        scn[tid + 256] += a1;
        __syncthreads();
    }
    for (int t = tid; t < 512; t += 256) {
        u32 c = cnt[t];
        u32 st = scn[t] - c;
        lpos[t] = st;
        cntg[(size_t)blk * NBK + t] = (u16)c;
        scng[(size_t)blk * NBK + t] = (u16)st;
    }
    __syncthreads();
#pragma unroll
    for (int j = 0; j < 16; ++j) {
        int lj = j * BS + tid;
        if (lj < ej) {
            int i = base + lj;
            int c = col[i];
            u32 p = atomicAdd(&lpos[c >> BSH], 1u);
            __half eh = __float2half(ew[i]);
            u64 en = (u64)(u32)row[i]
                   | ((u64)(u32)(c & 255) << 32)
                   | ((u64)(u16)__half_as_ushort(eh) << 48);
            pack[(size_t)blk * EPB2 + p] = en;
        }
    }
}

// ---- fused: 512 threads; even blocks: MFMA gemm 256 rows; odd: b2 ----
#define GBM3 256
#define XAP 40   // padded LDS stride (halves)
#define MAXB CAP

__global__ __launch_bounds__(512) void k_gb2(const float* __restrict__ x,
                                             const float* __restrict__ W,
                                             u16* __restrict__ hh, int n,
                                             const u16* __restrict__ cntg,
                                             const u16* __restrict__ scng,
                                             const u64* __restrict__ pack,
                                             u64* __restrict__ pack2,
                                             float* __restrict__ dinv,
                                             int* __restrict__ offs,
                                             int* __restrict__ ends,
                                             int nblk, int nbuck) {
    __shared__ __align__(16) u8 smem[38400];
    const int tid = threadIdx.x;
    const int bi = blockIdx.x;
    const bool isB2 = (bi & 1) && (bi >> 1) < nbuck;

    if (isB2) {
        // -------- b2 role: assemble bucket, counting sort, dinv, premult ----
        u32* lrow  = (u32*)smem;                  // [4608] 18 KB
        u16* lew   = (u16*)(smem + 18432);        // [4608] 9 KB
        u8*  lcl   = (u8*)(smem + 27648);         // [4608] 4.5 KB
        u32* cnt   = (u32*)(smem + 32256);        // [256] 1 KB
        float* wdeg= (float*)(smem + 33280);      // [256] 1 KB
        u32* pos   = (u32*)(smem + 34304);        // [256] 1 KB
        float* ldsd= (float*)(smem + 35328);      // [256] 1 KB
        u32* s     = (u32*)(smem + 36352);        // [512] 2 KB
        int b = bi >> 1;

        if (tid < 256) { cnt[tid] = 0; wdeg[tid] = 0.0f; }
        u32 myLen = 0, myStart = 0;
        if (tid < nblk) {
            myLen   = cntg[(size_t)tid * NBK + b];
            myStart = (u32)tid * EPB2 + scng[(size_t)tid * NBK + b];
        }
        s[tid] = myLen;
        __syncthreads();
        for (int off = 1; off < 512; off <<= 1) {
            u32 t = (tid >= off) ? s[tid - off] : 0u;
            __syncthreads();
            s[tid] += t;
            __syncthreads();
        }
        u32 base = s[tid] - myLen;
        int size = (int)s[511]; if (size > MAXB) size = MAXB;
        for (u32 k = 0; k < myLen; ++k) {
            u32 idx = base + k;
            if (idx < (u32)MAXB) {
                u64 en = pack[myStart + k];
                u32 cl = (u32)(en >> 32) & 255u;
                u16 eh = (u16)(en >> 48);
                lrow[idx] = (u32)en;
                lcl[idx] = (u8)cl;
                lew[idx] = eh;
                atomicAdd(&cnt[cl], 1u);
                atomicAdd(&wdeg[cl], __half2float(__ushort_as_half(eh)));
            }
        }
        __syncthreads();
        u32 myc = (tid < 256) ? cnt[tid] : 0;
        for (int off = 1; off < 256; off <<= 1) {
            u32 t = 0;
            if (tid < 256 && tid >= (u32)off) t = cnt[tid - off];
            __syncthreads();
            if (tid < 256) cnt[tid] += t;
            __syncthreads();
        }
        size_t gbase = (size_t)b * CAP;
        if (tid < 256) {
            u32 st = cnt[tid] - myc;
            pos[tid] = st;
            float dv = rsqrtf(1.0f + wdeg[tid]);
            ldsd[tid] = dv;
            int c = (b << BSH) + tid;
            if (c < n) {
                dinv[c] = dv;
                offs[c] = (int)(gbase + st);
                ends[c] = (int)(gbase + st + myc);
            }
        }
        __syncthreads();
        for (int j = tid; j < size; j += 512) {
            u32 cl = lcl[j];
            u32 r = atomicAdd(&pos[cl], 1u);
            float w = __half2float(__ushort_as_half(lew[j])) * ldsd[cl];
            pack2[gbase + r] = ((u64)__float_as_uint(w) << 32) | (u64)lrow[j];
        }
        return;
    }
    // -------- MFMA GEMM role: 256 rows x 64 cols, BK=32, 8 waves --------
    int b2before = (bi + 1) >> 1; if (b2before > nbuck) b2before = nbuck;
    const int gid = bi - b2before;
    u16* xa = (u16*)smem;             // [256*40] 20 KB
    u16* wt = (u16*)(smem + 20480);   // [64*40]  5 KB
    const int lane = tid & 63;
    const int wid  = tid >> 6;        // 0..7
    const int lr = lane & 15;
    const int lg = lane >> 4;
    const int rb = gid * GBM3;
    const int wrow = wid * 32;

    f32x4 acc[2][4];
#pragma unroll
    for (int rt = 0; rt < 2; ++rt)
#pragma unroll
        for (int ct = 0; ct < 4; ++ct) acc[rt][ct] = (f32x4){0.f, 0.f, 0.f, 0.f};

    const int srow = tid >> 1;            // 0..255
    const int skh  = (tid & 1) * 16;
    const int wc   = tid & 63;            // W col
    const int wkb  = (tid >> 6) * 4;      // W k-base (0,4,..,28)

    for (int kc = 0; kc < 256; kc += 32) {
        {
            int gr = rb + srow; if (gr >= n) gr = n - 1;
            const float4* src = reinterpret_cast<const float4*>(&x[(size_t)gr * 256 + kc + skh]);
            float4 a0 = src[0], a1 = src[1], a2 = src[2], a3 = src[3];
            uint4 v0, v1;
            v0.x = pack2bf(a0.x, a0.y); v0.y = pack2bf(a0.z, a0.w);
            v0.z = pack2bf(a1.x, a1.y); v0.w = pack2bf(a1.z, a1.w);
            v1.x = pack2bf(a2.x, a2.y); v1.y = pack2bf(a2.z, a2.w);
            v1.z = pack2bf(a3.x, a3.y); v1.w = pack2bf(a3.z, a3.w);
            *reinterpret_cast<uint4*>(&xa[srow * XAP + skh]) = v0;
            *reinterpret_cast<uint4*>(&xa[srow * XAP + skh + 8]) = v1;
        }
        {
            float w0 = W[(size_t)(kc + wkb + 0) * 64 + wc];
            float w1 = W[(size_t)(kc + wkb + 1) * 64 + wc];
            float w2 = W[(size_t)(kc + wkb + 2) * 64 + wc];
            float w3 = W[(size_t)(kc + wkb + 3) * 64 + wc];
            u32* dst = reinterpret_cast<u32*>(&wt[wc * XAP + wkb]);
            dst[0] = pack2bf(w0, w1);
            dst[1] = pack2bf(w2, w3);
        }
        __syncthreads();

        bf16x8 af0 = *reinterpret_cast<const bf16x8*>(&xa[(wrow + lr) * XAP + lg * 8]);
        bf16x8 af1 = *reinterpret_cast<const bf16x8*>(&xa[(wrow + 16 + lr) * XAP + lg * 8]);
#pragma unroll
        for (int ct = 0; ct < 4; ++ct) {
            bf16x8 bfr = *reinterpret_cast<const bf16x8*>(&wt[(ct * 16 + lr) * XAP + lg * 8]);
            acc[0][ct] = __builtin_amdgcn_mfma_f32_16x16x32_bf16(af0, bfr, acc[0][ct], 0, 0, 0);
            acc[1][ct] = __builtin_amdgcn_mfma_f32_16x16x32_bf16(af1, bfr, acc[1][ct], 0, 0, 0);
        }
        __syncthreads();
    }

    // coalesced epilogue: stage fp16 tile in LDS, then uint4 copy-out.
    u16* eo = (u16*)smem;     // [256][64] u16 = 32 KB
#pragma unroll
    for (int rt = 0; rt < 2; ++rt) {
#pragma unroll
        for (int reg = 0; reg < 4; ++reg) {
            int r = wrow + rt * 16 + lg * 4 + reg;
#pragma unroll
            for (int ct = 0; ct < 4; ++ct) {
                eo[r * 64 + ct * 16 + lr] =
                    __half_as_ushort(__float2half(acc[rt][ct][reg]));
            }
        }
    }
    __syncthreads();
    {
        const uint4* src = reinterpret_cast<const uint4*>(eo);
        uint4* dst = reinterpret_cast<uint4*>(hh + (size_t)rb * 64);
#pragma unroll
        for (int i = 0; i < 4; ++i) {
            int idx = i * 512 + tid;       // 2048 uint4; row = idx>>3
            if (rb + (idx >> 3) < n) dst[idx] = src[idx];
        }
    }
}

// one wave per node; lane = (edge parity, channel pair); entry = (row, w)
__global__ __launch_bounds__(BS) void k_reduce(const u64* __restrict__ sorted,
                                               const int* __restrict__ offs,
                                               const int* __restrict__ ends,
                                               const float* __restrict__ dinv,
                                               const __half2* __restrict__ hh,
                                               const float* __restrict__ bias,
                                               float* __restrict__ out, int n) {
    int node = blockIdx.x * 4 + (threadIdx.x >> 6);
    int lane = threadIdx.x & 63;
    if (node >= n) return;
    int cc  = lane & 31;
    int ehi = lane >> 5;
    int s = offs[node];
    int t = ends[node];
    float ax = 0.0f, ay = 0.0f;
    int j = s;
    for (; j + 7 < t; j += 8) {
        u64 p0 = sorted[j     + ehi];
        u64 p1 = sorted[j + 2 + ehi];
        u64 p2 = sorted[j + 4 + ehi];
        u64 p3 = sorted[j + 6 + ehi];
        int r0 = (int)(u32)p0, r1 = (int)(u32)p1, r2 = (int)(u32)p2, r3 = (int)(u32)p3;
        float n0 = __uint_as_float((u32)(p0 >> 32)) * dinv[r0];
        float n1 = __uint_as_float((u32)(p1 >> 32)) * dinv[r1];
        float n2 = __uint_as_float((u32)(p2 >> 32)) * dinv[r2];
        float n3 = __uint_as_float((u32)(p3 >> 32)) * dinv[r3];
        float2 f0 = __half22float2(hh[(size_t)r0 * 32 + cc]);
        float2 f1 = __half22float2(hh[(size_t)r1 * 32 + cc]);
        float2 f2 = __half22float2(hh[(size_t)r2 * 32 + cc]);
        float2 f3 = __half22float2(hh[(size_t)r3 * 32 + cc]);
        ax += n0 * f0.x; ay += n0 * f0.y;
        ax += n1 * f1.x; ay += n1 * f1.y;
        ax += n2 * f2.x; ay += n2 * f2.y;
        ax += n3 * f3.x; ay += n3 * f3.y;
    }
    for (; j + 1 < t; j += 2) {
        u64 p = sorted[j + ehi];
        int r = (int)(u32)p;
        float nn = __uint_as_float((u32)(p >> 32)) * dinv[r];
        float2 f = __half22float2(hh[(size_t)r * 32 + cc]);
        ax += nn * f.x; ay += nn * f.y;
    }
    if (j < t && ehi == 0) {
        u64 p = sorted[j];
        int r = (int)(u32)p;
        float nn = __uint_as_float((u32)(p >> 32)) * dinv[r];
        float2 f = __half22float2(hh[(size_t)r * 32 + cc]);
        ax += nn * f.x; ay += nn * f.y;
    }
    ax += __shfl_xor(ax, 32);
    ay += __shfl_xor(ay, 32);
    if (ehi == 0) {
        float di = dinv[node];
        float2 fs = __half22float2(hh[(size_t)node * 32 + cc]);
        float2 bb = *reinterpret_cast<const float2*>(&bias[cc * 2]);
        float2 r;
        r.x = ax + di * di * fs.x + bb.x;
        r.y = ay + di * di * fs.y + bb.y;
        reinterpret_cast<float2*>(out)[(size_t)node * 32 + cc] = r;
    }
}

// ---------------- fallback (atomic path, fp32) if ws too small ----------------
__global__ __launch_bounds__(BS) void k_init_f(float* __restrict__ deg, int n) {
    int i = blockIdx.x * BS + threadIdx.x;
    if (i < n) deg[i] = 1.0f;
}
__global__ __launch_bounds__(BS) void k_count_f(const int* __restrict__ col,
                                                const float* __restrict__ ew,
                                                float* __restrict__ deg, int e) {
    int i = blockIdx.x * BS + threadIdx.x;
    if (i < e) unsafeAtomicAdd(&deg[col[i]], ew[i]);
}
__global__ __launch_bounds__(BS) void k_dinv_f(float* __restrict__ deg, int n) {
    int i = blockIdx.x * BS + threadIdx.x;
    if (i < n) {
        float d = deg[i];
        deg[i] = d > 0.0f ? rsqrtf(d) : 0.0f;
    }
}
__global__ __launch_bounds__(BS) void k_gemm_f(const float* __restrict__ x,
                                               const float* __restrict__ W,
                                               float* __restrict__ h, int n) {
    __shared__ float xsh[4 * 256];
    int b0 = blockIdx.x * 4;
    const float4* xv = reinterpret_cast<const float4*>(x + (size_t)b0 * 256);
    reinterpret_cast<float4*>(xsh)[threadIdx.x] = xv[threadIdx.x];
    __syncthreads();
    int rl = threadIdx.x >> 6;
    int c  = threadIdx.x & 63;
    const float* xr = xsh + rl * 256;
    float acc = 0.0f;
#pragma unroll 8
    for (int k = 0; k < 256; ++k) acc += xr[k] * W[k * 64 + c];
    int r = b0 + rl;
    if (r < n) h[(size_t)r * 64 + c] = acc;
}
__global__ __launch_bounds__(BS) void k_out_init(const float* __restrict__ h,
                                                 const float* __restrict__ dinv,
                                                 const float* __restrict__ bias,
                                                 float* __restrict__ out, int n64) {
    int i = blockIdx.x * BS + threadIdx.x;
    if (i < n64) {
        int r = i >> 6, c = i & 63;
        float di = dinv[r];
        out[i] = bias[c] + di * di * h[i];
    }
}
__global__ __launch_bounds__(BS) void k_scatter(const int* __restrict__ row,
                                                const int* __restrict__ col,
                                                const float* __restrict__ ew,
                                                const float* __restrict__ dinv,
                                                const float* __restrict__ h,
                                                float* __restrict__ out, int e) {
    int idx = blockIdx.x * BS + threadIdx.x;
    int ei = idx >> 6;
    int c  = idx & 63;
    if (ei >= e) return;
    int r = row[ei];
    int t = col[ei];
    float nrm = dinv[r] * ew[ei] * dinv[t];
    unsafeAtomicAdd(&out[(size_t)t * 64 + c], nrm * h[(size_t)r * 64 + c]);
}

extern "C" void kernel_launch(void* const* d_in, const int* in_sizes, int n_in,
                              void* d_out, int out_size, void* d_ws, size_t ws_size,
                              hipStream_t stream) {
    const float* x   = (const float*)d_in[0];
    const int*   ei  = (const int*)d_in[1];
    const float* ew  = (const float*)d_in[2];
    const float* W   = (const float*)d_in[3];
    const float* b   = (const float*)d_in[4];
    float* out = (float*)d_out;

    const int n = in_sizes[0] / 256;       // 100000
    const int e = in_sizes[1] / 2;         // 1600000
    const int* row = ei;
    const int* col = ei + e;
    const int nbuck = (n + 255) >> 8;        // 391
    const int nblk2 = (e + EPB2 - 1) / EPB2; // 391
    const int ngemm = (n + GBM3 - 1) / GBM3; // 391

    size_t off = 0;
    auto alloc = [&](size_t elems) { size_t p = off; off += (elems + 63) & ~63ull; return p; };
    size_t o_cntg  = alloc(((size_t)nblk2 * NBK + 1) / 2);
    size_t o_scng  = alloc(((size_t)nblk2 * NBK + 1) / 2);
    size_t o_pack  = alloc((size_t)nblk2 * EPB2 * 2);
    size_t o_pack2 = alloc((size_t)nbuck * CAP * 2);
    size_t o_offs  = alloc(n);
    size_t o_ends  = alloc(n);
    size_t o_dinv  = alloc(n);
    size_t o_h     = alloc((size_t)n * 32);
    size_t needed = off * 4;

    u32*   wsu = (u32*)d_ws;
    float* wsf = (float*)d_ws;
    int*   wsi = (int*)d_ws;

    if (ws_size >= needed) {
        u16*   cntg  = (u16*)(wsu + o_cntg);
        u16*   scng  = (u16*)(wsu + o_scng);
        u64*   pack  = (u64*)(wsu + o_pack);
        u64*   pack2 = (u64*)(wsu + o_pack2);
        int*   offs  = wsi + o_offs;
        int*   ends  = wsi + o_ends;
        float* dinv  = wsf + o_dinv;
        u16*   hh    = (u16*)(wsu + o_h);

        k_scat<<<nblk2, BS, 0, stream>>>(row, col, ew, cntg, scng, pack, e);
        k_gb2<<<ngemm + nbuck, 512, 0, stream>>>(x, W, hh, n, cntg, scng,
                                                 pack, pack2, dinv, offs, ends,
                                                 nblk2, nbuck);
        k_reduce<<<(n + 3) / 4, BS, 0, stream>>>(pack2, offs, ends, dinv,
                                                 (const __half2*)hh, b, out, n);
    } else {
        float* deg = wsf;
        float* h   = wsf + ((n + 63) & ~63);
        const int nb = (n + BS - 1) / BS;
        const int eb = (e + BS - 1) / BS;
        k_init_f<<<nb, BS, 0, stream>>>(deg, n);
        k_count_f<<<eb, BS, 0, stream>>>(col, ew, deg, e);
        k_dinv_f<<<nb, BS, 0, stream>>>(deg, n);
        k_gemm_f<<<(n + 3) / 4, BS, 0, stream>>>(x, W, h, n);
        k_out_init<<<((n * 64) + BS - 1) / BS, BS, 0, stream>>>(h, deg, b, out, n * 64);
        k_scatter<<<((size_t)e * 64 + BS - 1) / BS, BS, 0, stream>>>(row, col, ew, deg, h, out, e);
    }
}

// Round 24
// 123.288 us; speedup vs baseline: 1.0985x; 1.0985x over previous
//
#include <hip/hip_runtime.h>
#include <hip/hip_fp16.h>

// GCN conv: out[c] = sum_{edges->c} norm * h[row] + dinv[c]^2 * h[c] + b
// N=100000, E=1600000, IN_C=256, OUT_C=64
// FINAL (round-20 best, 123.8 us): block-major scatter (zero global atomics):
//   k_g4 {MFMA bf16 gemm (coalesced epilogue) ||interleaved|| hist+LDS-sort ->
//   CONTIGUOUS per-block pack write + per-(block,bucket) u16 metadata}
//   -> k_b2 (per-bucket: metadata scan + run-gather into LDS, counting sort,
//            wdeg->dinv, norm premult, coalesced write to pack2, offs/ends)
//   -> k_reduce (segmented reduce, fp16 gather, 8-edge ILP)

#define BS 256
#define EPB2 4096           // edges per scatter block
#define BSH 8               // bucket = col >> 8
#define CAP 4608            // bucket staging capacity (mean 4092 + 8 sigma)
#define NBK 512             // metadata row stride (buckets padded to 512)

typedef unsigned long long u64;
typedef unsigned int u32;
typedef unsigned short u16;
typedef unsigned char u8;

typedef __attribute__((ext_vector_type(8))) short bf16x8;
typedef __attribute__((ext_vector_type(4))) float f32x4;

__device__ inline u16 f2bf(float f) {          // RNE fp32 -> bf16
    u32 u = __float_as_uint(f);
    return (u16)((u + 0x7fffu + ((u >> 16) & 1u)) >> 16);
}
__device__ inline u32 pack2bf(float a, float b) {
    return (u32)f2bf(a) | ((u32)f2bf(b) << 16);
}

// ---- fused: interleaved roles; scatter iff (bi%3==2 && bi/3<nblk2) ----
#define GBM2 128
#define XAP 40   // padded LDS stride (halves)

__global__ __launch_bounds__(BS) void k_g4(const float* __restrict__ x,
                                           const float* __restrict__ W,
                                           u16* __restrict__ hh, int n,
                                           const int* __restrict__ row,
                                           const int* __restrict__ col,
                                           const float* __restrict__ ew,
                                           u16* __restrict__ cntg,
                                           u16* __restrict__ scng,
                                           u64* __restrict__ pack,
                                           int nbuck, int nblk2, int e) {
    __shared__ __align__(16) u8 smem[24576];
    const int tid = threadIdx.x;
    const int bi = blockIdx.x;
    const bool isScatter = ((bi % 3) == 2) && (bi / 3 < nblk2);

    if (isScatter) {
        // ---- scatter role: 4096 edges -> locally-sorted CONTIGUOUS write ----
        u16* bkt  = (u16*)smem;                 // [4096] 8 KB
        u16* sidx = (u16*)(smem + 8192);        // [4096] 8 KB
        u32* cnt  = (u32*)(smem + 16384);       // [512]  2 KB
        u32* scn  = (u32*)(smem + 18432);       // [512]  2 KB
        u32* lpos = (u32*)(smem + 20480);       // [512]  2 KB
        int blk = bi / 3;
        int base = blk * EPB2;
        int ej = e - base; if (ej > EPB2) ej = EPB2;

        cnt[tid] = 0; cnt[tid + 256] = 0;
        __syncthreads();
#pragma unroll
        for (int j = 0; j < 16; ++j) {
            int lj = j * BS + tid;
            if (lj < ej) {
                int b = col[base + lj] >> BSH;
                bkt[lj] = (u16)b;
                atomicAdd(&cnt[b], 1u);
            }
        }
        __syncthreads();
        // inclusive scan of cnt[0..512) -> scn
        scn[tid] = cnt[tid];
        scn[tid + 256] = cnt[tid + 256];
        __syncthreads();
        for (int off = 1; off < 512; off <<= 1) {
            u32 a0 = (tid >= off) ? scn[tid - off] : 0u;
            u32 a1 = scn[tid + 256 - off];
            __syncthreads();
            scn[tid] += a0;
            scn[tid + 256] += a1;
            __syncthreads();
        }
        // metadata out (coalesced); lpos = local start
        for (int t = tid; t < 512; t += 256) {
            u32 c = cnt[t];
            u32 st = scn[t] - c;
            lpos[t] = st;
            cntg[(size_t)blk * NBK + t] = (u16)c;
            scng[(size_t)blk * NBK + t] = (u16)st;
        }
        __syncthreads();
        // build bucket-sorted index
#pragma unroll
        for (int j = 0; j < 16; ++j) {
            int lj = j * BS + tid;
            if (lj < ej) {
                u32 p = atomicAdd(&lpos[bkt[lj]], 1u);
                sidx[p] = (u16)lj;
            }
        }
        __syncthreads();
        // fully coalesced contiguous write
        for (int p = tid; p < ej; p += 256) {
            int lj = sidx[p];
            int i = base + lj;
            __half eh = __float2half(ew[i]);
            u64 en = (u64)(u32)row[i]
                   | ((u64)(u32)(col[i] & 255) << 32)
                   | ((u64)(u16)__half_as_ushort(eh) << 48);
            pack[(size_t)blk * EPB2 + p] = en;
        }
        return;
    }
    // -------- MFMA GEMM role: 128 rows x 64 cols, BK=32 --------
    int sbefore = bi / 3; if (sbefore > nblk2) sbefore = nblk2;
    const int gid = bi - sbefore;
    u16* xa = (u16*)smem;             // [128*40] 10 KB
    u16* wt = (u16*)(smem + 10240);   // [64*40]  5 KB
    const int lane = tid & 63;
    const int wid  = tid >> 6;
    const int lr = lane & 15;
    const int lg = lane >> 4;
    const int rb = gid * GBM2;
    const int wrow = wid * 32;

    f32x4 acc[2][4];
#pragma unroll
    for (int rt = 0; rt < 2; ++rt)
#pragma unroll
        for (int ct = 0; ct < 4; ++ct) acc[rt][ct] = (f32x4){0.f, 0.f, 0.f, 0.f};

    const int srow = tid >> 1;
    const int skh  = (tid & 1) * 16;
    const int wc   = tid >> 2;
    const int wk   = (tid & 3) * 8;

    for (int kc = 0; kc < 256; kc += 32) {
        {
            int gr = rb + srow; if (gr >= n) gr = n - 1;
            const float4* src = reinterpret_cast<const float4*>(&x[(size_t)gr * 256 + kc + skh]);
            float4 a0 = src[0], a1 = src[1], a2 = src[2], a3 = src[3];
            uint4 v0, v1;
            v0.x = pack2bf(a0.x, a0.y); v0.y = pack2bf(a0.z, a0.w);
            v0.z = pack2bf(a1.x, a1.y); v0.w = pack2bf(a1.z, a1.w);
            v1.x = pack2bf(a2.x, a2.y); v1.y = pack2bf(a2.z, a2.w);
            v1.z = pack2bf(a3.x, a3.y); v1.w = pack2bf(a3.z, a3.w);
            *reinterpret_cast<uint4*>(&xa[srow * XAP + skh]) = v0;
            *reinterpret_cast<uint4*>(&xa[srow * XAP + skh + 8]) = v1;
        }
        {
            float w0 = W[(size_t)(kc + wk + 0) * 64 + wc];
            float w1 = W[(size_t)(kc + wk + 1) * 64 + wc];
            float w2 = W[(size_t)(kc + wk + 2) * 64 + wc];
            float w3 = W[(size_t)(kc + wk + 3) * 64 + wc];
            float w4 = W[(size_t)(kc + wk + 4) * 64 + wc];
            float w5 = W[(size_t)(kc + wk + 5) * 64 + wc];
            float w6 = W[(size_t)(kc + wk + 6) * 64 + wc];
            float w7 = W[(size_t)(kc + wk + 7) * 64 + wc];
            u32* dst = reinterpret_cast<u32*>(&wt[wc * XAP + wk]);
            dst[0] = pack2bf(w0, w1);
            dst[1] = pack2bf(w2, w3);
            dst[2] = pack2bf(w4, w5);
            dst[3] = pack2bf(w6, w7);
        }
        __syncthreads();

        bf16x8 af0 = *reinterpret_cast<const bf16x8*>(&xa[(wrow + lr) * XAP + lg * 8]);
        bf16x8 af1 = *reinterpret_cast<const bf16x8*>(&xa[(wrow + 16 + lr) * XAP + lg * 8]);
#pragma unroll
        for (int ct = 0; ct < 4; ++ct) {
            bf16x8 bfr = *reinterpret_cast<const bf16x8*>(&wt[(ct * 16 + lr) * XAP + lg * 8]);
            acc[0][ct] = __builtin_amdgcn_mfma_f32_16x16x32_bf16(af0, bfr, acc[0][ct], 0, 0, 0);
            acc[1][ct] = __builtin_amdgcn_mfma_f32_16x16x32_bf16(af1, bfr, acc[1][ct], 0, 0, 0);
        }
        __syncthreads();
    }

    // coalesced epilogue: stage fp16 tile in LDS, then uint4 copy-out.
    u16* eo = (u16*)smem;     // [128][64] u16 = 16 KB
#pragma unroll
    for (int rt = 0; rt < 2; ++rt) {
#pragma unroll
        for (int reg = 0; reg < 4; ++reg) {
            int r = wrow + rt * 16 + lg * 4 + reg;
#pragma unroll
            for (int ct = 0; ct < 4; ++ct) {
                eo[r * 64 + ct * 16 + lr] =
                    __half_as_ushort(__float2half(acc[rt][ct][reg]));
            }
        }
    }
    __syncthreads();
    {
        const uint4* src = reinterpret_cast<const uint4*>(eo);
        uint4* dst = reinterpret_cast<uint4*>(hh + (size_t)rb * 64);
#pragma unroll
        for (int i = 0; i < 4; ++i) {
            int idx = i * BS + tid;          // uint4 index 0..1023; row = idx>>3
            if (rb + (idx >> 3) < n) dst[idx] = src[idx];
        }
    }
}

// ---- level-2: assemble bucket from block runs; counting sort; dinv/offs/ends ----
#define MAXB CAP
__global__ __launch_bounds__(512) void k_b2(const u16* __restrict__ cntg,
                                            const u16* __restrict__ scng,
                                            const u64* __restrict__ pack,
                                            u64* __restrict__ pack2,
                                            float* __restrict__ dinv,
                                            int* __restrict__ offs,
                                            int* __restrict__ ends,
                                            int n, int nblk) {
    __shared__ u32 lrow[MAXB];       // 18 KB
    __shared__ u16 lew[MAXB];        // 9 KB
    __shared__ u8  lcl[MAXB];        // 4.5 KB
    __shared__ u32 cnt[256];
    __shared__ float wdeg[256];
    __shared__ u32 pos[256];
    __shared__ float ldsd[256];
    __shared__ u32 s[512];
    int b = blockIdx.x;
    int tid = threadIdx.x;

    if (tid < 256) { cnt[tid] = 0; wdeg[tid] = 0.0f; }
    // per-block run metadata for this bucket
    u32 myLen = 0, myStart = 0;
    if (tid < nblk) {
        myLen   = cntg[(size_t)tid * NBK + b];
        myStart = (u32)tid * EPB2 + scng[(size_t)tid * NBK + b];
    }
    s[tid] = myLen;
    __syncthreads();
    for (int off = 1; off < 512; off <<= 1) {
        u32 t = (tid >= off) ? s[tid - off] : 0u;
        __syncthreads();
        s[tid] += t;
        __syncthreads();
    }
    u32 base = s[tid] - myLen;
    int size = (int)s[511]; if (size > MAXB) size = MAXB;
    // gather this bucket's runs into LDS staging
    for (u32 k = 0; k < myLen; ++k) {
        u32 idx = base + k;
        if (idx < (u32)MAXB) {
            u64 en = pack[myStart + k];
            u32 cl = (u32)(en >> 32) & 255u;
            u16 eh = (u16)(en >> 48);
            lrow[idx] = (u32)en;
            lcl[idx] = (u8)cl;
            lew[idx] = eh;
            atomicAdd(&cnt[cl], 1u);
            atomicAdd(&wdeg[cl], __half2float(__ushort_as_half(eh)));
        }
    }
    __syncthreads();
    u32 myc = (tid < 256) ? cnt[tid] : 0;
    for (int off = 1; off < 256; off <<= 1) {
        u32 t = 0;
        if (tid < 256 && tid >= (u32)off) t = cnt[tid - off];
        __syncthreads();
        if (tid < 256) cnt[tid] += t;
        __syncthreads();
    }
    size_t gbase = (size_t)b * CAP;
    if (tid < 256) {
        u32 st = cnt[tid] - myc;
        pos[tid] = st;
        float dv = rsqrtf(1.0f + wdeg[tid]);
        ldsd[tid] = dv;
        int c = (b << BSH) + tid;
        if (c < n) {
            dinv[c] = dv;
            offs[c] = (int)(gbase + st);
            ends[c] = (int)(gbase + st + myc);
        }
    }
    __syncthreads();
    for (int j = tid; j < size; j += 512) {
        u32 cl = lcl[j];
        u32 r = atomicAdd(&pos[cl], 1u);
        float w = __half2float(__ushort_as_half(lew[j])) * ldsd[cl];
        pack2[gbase + r] = ((u64)__float_as_uint(w) << 32) | (u64)lrow[j];
    }
}

// one wave per node; lane = (edge parity, channel pair); entry = (row, w)
__global__ __launch_bounds__(BS) void k_reduce(const u64* __restrict__ sorted,
                                               const int* __restrict__ offs,
                                               const int* __restrict__ ends,
                                               const float* __restrict__ dinv,
                                               const __half2* __restrict__ hh,
                                               const float* __restrict__ bias,
                                               float* __restrict__ out, int n) {
    int node = blockIdx.x * 4 + (threadIdx.x >> 6);
    int lane = threadIdx.x & 63;
    if (node >= n) return;
    int cc  = lane & 31;
    int ehi = lane >> 5;
    int s = offs[node];
    int t = ends[node];
    float ax = 0.0f, ay = 0.0f;
    int j = s;
    for (; j + 7 < t; j += 8) {
        u64 p0 = sorted[j     + ehi];
        u64 p1 = sorted[j + 2 + ehi];
        u64 p2 = sorted[j + 4 + ehi];
        u64 p3 = sorted[j + 6 + ehi];
        int r0 = (int)(u32)p0, r1 = (int)(u32)p1, r2 = (int)(u32)p2, r3 = (int)(u32)p3;
        float n0 = __uint_as_float((u32)(p0 >> 32)) * dinv[r0];
        float n1 = __uint_as_float((u32)(p1 >> 32)) * dinv[r1];
        float n2 = __uint_as_float((u32)(p2 >> 32)) * dinv[r2];
        float n3 = __uint_as_float((u32)(p3 >> 32)) * dinv[r3];
        float2 f0 = __half22float2(hh[(size_t)r0 * 32 + cc]);
        float2 f1 = __half22float2(hh[(size_t)r1 * 32 + cc]);
        float2 f2 = __half22float2(hh[(size_t)r2 * 32 + cc]);
        float2 f3 = __half22float2(hh[(size_t)r3 * 32 + cc]);
        ax += n0 * f0.x; ay += n0 * f0.y;
        ax += n1 * f1.x; ay += n1 * f1.y;
        ax += n2 * f2.x; ay += n2 * f2.y;
        ax += n3 * f3.x; ay += n3 * f3.y;
    }
    for (; j + 1 < t; j += 2) {
        u64 p = sorted[j + ehi];
        int r = (int)(u32)p;
        float nn = __uint_as_float((u32)(p >> 32)) * dinv[r];
        float2 f = __half22float2(hh[(size_t)r * 32 + cc]);
        ax += nn * f.x; ay += nn * f.y;
    }
    if (j < t && ehi == 0) {
        u64 p = sorted[j];
        int r = (int)(u32)p;
        float nn = __uint_as_float((u32)(p >> 32)) * dinv[r];
        float2 f = __half22float2(hh[(size_t)r * 32 + cc]);
        ax += nn * f.x; ay += nn * f.y;
    }
    ax += __shfl_xor(ax, 32);
    ay += __shfl_xor(ay, 32);
    if (ehi == 0) {
        float di = dinv[node];
        float2 fs = __half22float2(hh[(size_t)node * 32 + cc]);
        float2 bb = *reinterpret_cast<const float2*>(&bias[cc * 2]);
        float2 r;
        r.x = ax + di * di * fs.x + bb.x;
        r.y = ay + di * di * fs.y + bb.y;
        reinterpret_cast<float2*>(out)[(size_t)node * 32 + cc] = r;
    }
}

// ---------------- fallback (atomic path, fp32) if ws too small ----------------
__global__ __launch_bounds__(BS) void k_init_f(float* __restrict__ deg, int n) {
    int i = blockIdx.x * BS + threadIdx.x;
    if (i < n) deg[i] = 1.0f;
}
__global__ __launch_bounds__(BS) void k_count_f(const int* __restrict__ col,
                                                const float* __restrict__ ew,
                                                float* __restrict__ deg, int e) {
    int i = blockIdx.x * BS + threadIdx.x;
    if (i < e) unsafeAtomicAdd(&deg[col[i]], ew[i]);
}
__global__ __launch_bounds__(BS) void k_dinv_f(float* __restrict__ deg, int n) {
    int i = blockIdx.x * BS + threadIdx.x;
    if (i < n) {
        float d = deg[i];
        deg[i] = d > 0.0f ? rsqrtf(d) : 0.0f;
    }
}
__global__ __launch_bounds__(BS) void k_gemm_f(const float* __restrict__ x,
                                               const float* __restrict__ W,
                                               float* __restrict__ h, int n) {
    __shared__ float xsh[4 * 256];
    int b0 = blockIdx.x * 4;
    const float4* xv = reinterpret_cast<const float4*>(x + (size_t)b0 * 256);
    reinterpret_cast<float4*>(xsh)[threadIdx.x] = xv[threadIdx.x];
    __syncthreads();
    int rl = threadIdx.x >> 6;
    int c  = threadIdx.x & 63;
    const float* xr = xsh + rl * 256;
    float acc = 0.0f;
#pragma unroll 8
    for (int k = 0; k < 256; ++k) acc += xr[k] * W[k * 64 + c];
    int r = b0 + rl;
    if (r < n) h[(size_t)r * 64 + c] = acc;
}
__global__ __launch_bounds__(BS) void k_out_init(const float* __restrict__ h,
                                                 const float* __restrict__ dinv,
                                                 const float* __restrict__ bias,
                                                 float* __restrict__ out, int n64) {
    int i = blockIdx.x * BS + threadIdx.x;
    if (i < n64) {
        int r = i >> 6, c = i & 63;
        float di = dinv[r];
        out[i] = bias[c] + di * di * h[i];
    }
}
__global__ __launch_bounds__(BS) void k_scatter(const int* __restrict__ row,
                                                const int* __restrict__ col,
                                                const float* __restrict__ ew,
                                                const float* __restrict__ dinv,
                                                const float* __restrict__ h,
                                                float* __restrict__ out, int e) {
    int idx = blockIdx.x * BS + threadIdx.x;
    int ei = idx >> 6;
    int c  = idx & 63;
    if (ei >= e) return;
    int r = row[ei];
    int t = col[ei];
    float nrm = dinv[r] * ew[ei] * dinv[t];
    unsafeAtomicAdd(&out[(size_t)t * 64 + c], nrm * h[(size_t)r * 64 + c]);
}

extern "C" void kernel_launch(void* const* d_in, const int* in_sizes, int n_in,
                              void* d_out, int out_size, void* d_ws, size_t ws_size,
                              hipStream_t stream) {
    const float* x   = (const float*)d_in[0];
    const int*   ei  = (const int*)d_in[1];
    const float* ew  = (const float*)d_in[2];
    const float* W   = (const float*)d_in[3];
    const float* b   = (const float*)d_in[4];
    float* out = (float*)d_out;

    const int n = in_sizes[0] / 256;       // 100000
    const int e = in_sizes[1] / 2;         // 1600000
    const int* row = ei;
    const int* col = ei + e;
    const int nbuck = (n + 255) >> 8;        // 391
    const int nblk2 = (e + EPB2 - 1) / EPB2; // 391
    const int ngemm = (n + GBM2 - 1) / GBM2; // 782

    size_t off = 0;
    auto alloc = [&](size_t elems) { size_t p = off; off += (elems + 63) & ~63ull; return p; };
    size_t o_cntg  = alloc(((size_t)nblk2 * NBK + 1) / 2);  // u16[nblk2*512]
    size_t o_scng  = alloc(((size_t)nblk2 * NBK + 1) / 2);  // u16[nblk2*512]
    size_t o_pack  = alloc((size_t)nblk2 * EPB2 * 2);       // u64, block-major
    size_t o_pack2 = alloc((size_t)nbuck * CAP * 2);        // u64, bucket-major
    size_t o_offs  = alloc(n);
    size_t o_ends  = alloc(n);
    size_t o_dinv  = alloc(n);
    size_t o_h     = alloc((size_t)n * 32);                 // half[n*64]
    size_t needed = off * 4;

    u32*   wsu = (u32*)d_ws;
    float* wsf = (float*)d_ws;
    int*   wsi = (int*)d_ws;

    if (ws_size >= needed) {
        u16*   cntg  = (u16*)(wsu + o_cntg);
        u16*   scng  = (u16*)(wsu + o_scng);
        u64*   pack  = (u64*)(wsu + o_pack);
        u64*   pack2 = (u64*)(wsu + o_pack2);
        int*   offs  = wsi + o_offs;
        int*   ends  = wsi + o_ends;
        float* dinv  = wsf + o_dinv;
        u16*   hh    = (u16*)(wsu + o_h);

        k_g4<<<ngemm + nblk2, BS, 0, stream>>>(x, W, hh, n,
                                               row, col, ew, cntg, scng, pack,
                                               nbuck, nblk2, e);
        k_b2<<<nbuck, 512, 0, stream>>>(cntg, scng, pack, pack2,
                                        dinv, offs, ends, n, nblk2);
        k_reduce<<<(n + 3) / 4, BS, 0, stream>>>(pack2, offs, ends, dinv,
                                                 (const __half2*)hh, b, out, n);
    } else {
        float* deg = wsf;
        float* h   = wsf + ((n + 63) & ~63);
        const int nb = (n + BS - 1) / BS;
        const int eb = (e + BS - 1) / BS;
        k_init_f<<<nb, BS, 0, stream>>>(deg, n);
        k_count_f<<<eb, BS, 0, stream>>>(col, ew, deg, e);
        k_dinv_f<<<nb, BS, 0, stream>>>(deg, n);
        k_gemm_f<<<(n + 3) / 4, BS, 0, stream>>>(x, W, h, n);
        k_out_init<<<((n * 64) + BS - 1) / BS, BS, 0, stream>>>(h, deg, b, out, n * 64);
        k_scatter<<<((size_t)e * 64 + BS - 1) / BS, BS, 0, stream>>>(row, col, ew, deg, h, out, e);
    }
}